// Round 3
// baseline (1378.084 us; speedup 1.0000x reference)
//
#include <hip/hip_runtime.h>

typedef __bf16 bf16;
typedef __attribute__((ext_vector_type(8))) __bf16 bf16x8;
typedef __attribute__((ext_vector_type(4))) float f32x4;
typedef __attribute__((ext_vector_type(8))) unsigned short u16x8;

#define MFMA16 __builtin_amdgcn_mfma_f32_16x16x32_bf16

// Problem constants
constexpr int NB = 4;      // B
constexpr int NL = 64;     // L == S
constexpr int NN = 768;    // nodes
constexpr int RROWS = NB * NL * NN;  // 196608 flat rows

// ---------------------------------------------------------------------------
// dtype-dispatch helpers: external inputs may be fp32 or bf16 (runtime flag)
// ---------------------------------------------------------------------------
__device__ __forceinline__ float loadsf(const void* base, size_t i, int isf) {
  return isf ? ((const float*)base)[i] : (float)((const bf16*)base)[i];
}

__device__ __forceinline__ bf16x8 load8f(const void* base, size_t eoff, int isf) {
  if (isf) {
    const float* p = (const float*)base + eoff;
    f32x4 a = *(const f32x4*)(p);
    f32x4 b = *(const f32x4*)(p + 4);
    bf16x8 r;
    r[0] = (bf16)a[0]; r[1] = (bf16)a[1]; r[2] = (bf16)a[2]; r[3] = (bf16)a[3];
    r[4] = (bf16)b[0]; r[5] = (bf16)b[1]; r[6] = (bf16)b[2]; r[7] = (bf16)b[3];
    return r;
  }
  return *(const bf16x8*)((const bf16*)base + eoff);
}

// ---------------------------------------------------------------------------
// flag: 1 if external tensors are fp32 (detected via bf16-NaN bit patterns
// appearing when fp32 mantissa halves are read as bf16), else 0.
// ---------------------------------------------------------------------------
__global__ void zero_flag_kernel(int* flag) { if (threadIdx.x == 0) *flag = 0; }

__global__ void detect_kernel(const unsigned short* __restrict__ q, int* flag) {
  size_t idx = (size_t)blockIdx.x * 256 + threadIdx.x;
  int found = 0;
  constexpr size_t CHUNKS = 12582912 / 8;  // scan 12.58M u16 (whole bf16 buf / half fp32 buf)
  for (size_t c = idx; c < CHUNKS; c += (size_t)64 * 256) {
    u16x8 v = *(const u16x8*)(q + c * 8);
#pragma unroll
    for (int j = 0; j < 8; ++j)
      if ((v[j] & 0x7F80) == 0x7F80) found = 1;  // exp all-ones: NaN/Inf bf16 pattern
  }
  if (__ballot(found)) {
    if ((threadIdx.x & 63) == 0) atomicOr(flag, 1);
  }
}

// ---------------------------------------------------------------------------
// prep: aT[w][v] = a[v][w]
// ---------------------------------------------------------------------------
__global__ void prep_aT_kernel(const void* __restrict__ a, const int* __restrict__ flagp,
                               bf16* __restrict__ aT) {
  const int isf = *flagp;
  int idx = blockIdx.x * 256 + threadIdx.x;
  if (idx < NN * NN) {
    int w = idx / NN, v = idx % NN;
    aT[idx] = (bf16)loadsf(a, (size_t)v * NN + w, isf);
  }
}

// ---------------------------------------------------------------------------
// prep: combined weights.  M_j[e,c] = sum_o Wp[e,o] * Wg[o, j*64+c]  (j=0,1,2)
//       beta[e] = sum_o Wp[e,o]*bg[o] + bp[e]
// M1 = j0 slice [64x64]; M23 = rows 0..63 <- j1 (y2), rows 64..127 <- j2 (y3)
// ---------------------------------------------------------------------------
__global__ void prep_w_kernel(const void* __restrict__ Wp, const void* __restrict__ bp,
                              const void* __restrict__ Wg, const void* __restrict__ bg,
                              const int* __restrict__ flagp,
                              bf16* __restrict__ M1, bf16* __restrict__ M23,
                              float* __restrict__ beta) {
  const int isf = *flagp;
  int t = threadIdx.x;
  for (int idx = t; idx < 3 * 4096; idx += 256) {
    int j = idx >> 12, rem = idx & 4095, e = rem >> 6, c = rem & 63;
    float s = 0.f;
    for (int o = 0; o < 64; ++o)
      s += loadsf(Wp, e * 64 + o, isf) * loadsf(Wg, o * 192 + j * 64 + c, isf);
    if (j == 0) M1[e * 64 + c] = (bf16)s;
    else        M23[((j - 1) * 64 + e) * 64 + c] = (bf16)s;
  }
  if (t < 64) {
    float s = loadsf(bp, t, isf);
    for (int o = 0; o < 64; ++o) s += loadsf(Wp, t * 64 + o, isf) * loadsf(bg, o, isf);
    beta[t] = s;
  }
}

// ---------------------------------------------------------------------------
// convert Wq,bq,Wo,bo -> internal bf16 slots
// ---------------------------------------------------------------------------
__global__ void conv_qo_kernel(const void* __restrict__ Wq, const void* __restrict__ bq,
                               const void* __restrict__ Wo, const void* __restrict__ bo,
                               const int* __restrict__ flagp,
                               bf16* __restrict__ WQc, bf16* __restrict__ BQc,
                               bf16* __restrict__ WOc, bf16* __restrict__ BOc) {
  const int isf = *flagp;
  int idx = blockIdx.x * 256 + threadIdx.x;
  if (idx < 4096)      WQc[idx]        = (bf16)loadsf(Wq, idx, isf);
  else if (idx < 4160) BQc[idx - 4096] = (bf16)loadsf(bq, idx - 4096, isf);
  else if (idx < 8256) WOc[idx - 4160] = (bf16)loadsf(Wo, idx - 4160, isf);
  else if (idx < 8320) BOc[idx - 8256] = (bf16)loadsf(bo, idx - 8256, isf);
}

// ---------------------------------------------------------------------------
// proj_rows: out[r][e] = sum_c in[r][c]*W[e][c] (+bias[e]) ; r in [r0, r0+128)
// in_ext: input dtype follows flag; out_ext: output dtype follows flag.
// ---------------------------------------------------------------------------
__global__ __launch_bounds__(256) void proj_rows_kernel(
    const void* in, const bf16* __restrict__ W,
    const bf16* __restrict__ bias, void* out,
    const int* __restrict__ flagp, int in_ext, int out_ext) {
  const int isf = *flagp;
  const int inf_ = in_ext & isf, outf = out_ext & isf;
  const int r0 = blockIdx.x * 128;
  const int t = threadIdx.x;
  const int wave = t >> 6, lane = t & 63;
  const int lane_r = lane & 15, quad = lane >> 4;
  const int m_base = wave * 32;

  __shared__ bf16 Al[128 * 72];
  __shared__ bf16 Bl[64 * 72];

  {
    int row = t >> 3, seg = t & 7;
#pragma unroll
    for (int j = 0; j < 4; ++j) {
      int r = row + j * 32;
      *(bf16x8*)&Al[r * 72 + seg * 8] = load8f(in, (size_t)(r0 + r) * 64 + seg * 8, inf_);
    }
#pragma unroll
    for (int j = 0; j < 2; ++j) {
      int u = t + j * 256;
      int br = u >> 3, bs_ = u & 7;
      *(u16x8*)&Bl[br * 72 + bs_ * 8] = *(const u16x8*)(W + (size_t)br * 64 + bs_ * 8);
    }
  }
  __syncthreads();

  f32x4 zero = {0.f, 0.f, 0.f, 0.f};
  f32x4 acc[2][4];
#pragma unroll
  for (int mt = 0; mt < 2; ++mt)
#pragma unroll
    for (int nt = 0; nt < 4; ++nt) acc[mt][nt] = zero;

#pragma unroll
  for (int ks = 0; ks < 2; ++ks) {
    bf16x8 af[2], bfr[4];
#pragma unroll
    for (int mt = 0; mt < 2; ++mt)
      af[mt] = *(const bf16x8*)&Al[(m_base + mt * 16 + lane_r) * 72 + ks * 32 + quad * 8];
#pragma unroll
    for (int nt = 0; nt < 4; ++nt)
      bfr[nt] = *(const bf16x8*)&Bl[(nt * 16 + lane_r) * 72 + ks * 32 + quad * 8];
#pragma unroll
    for (int mt = 0; mt < 2; ++mt)
#pragma unroll
      for (int nt = 0; nt < 4; ++nt)
        acc[mt][nt] = MFMA16(af[mt], bfr[nt], acc[mt][nt], 0, 0, 0);
  }

  float bv[4];
#pragma unroll
  for (int nt = 0; nt < 4; ++nt) bv[nt] = bias ? (float)bias[nt * 16 + lane_r] : 0.f;
#pragma unroll
  for (int mt = 0; mt < 2; ++mt) {
#pragma unroll
    for (int i = 0; i < 4; ++i) {
      int r = r0 + m_base + mt * 16 + quad * 4 + i;
#pragma unroll
      for (int nt = 0; nt < 4; ++nt) {
        float val = acc[mt][nt][i] + bv[nt];
        size_t o = (size_t)r * 64 + nt * 16 + lane_r;
        if (outf) ((float*)out)[o] = val;
        else      ((bf16*)out)[o] = (bf16)val;
      }
    }
  }
}

// ---------------------------------------------------------------------------
// projT: y{2,3}[bs][f][v] = sum_c M23[f(+64)][c] * x[bs*768+v][c]
// per block: one bs, 128-wide v tile. M=128(f), N=128(v), K=64.
// ---------------------------------------------------------------------------
__global__ __launch_bounds__(256) void projT_kernel(
    const void* __restrict__ x, const bf16* __restrict__ M23,
    bf16* __restrict__ y2out, bf16* __restrict__ y3out,
    const int* __restrict__ flagp) {
  const int isf = *flagp;
  const int v0 = blockIdx.x * 128;
  const int bs = blockIdx.y;
  const int t = threadIdx.x;
  const int wave = t >> 6, lane = t & 63;
  const int lane_r = lane & 15, quad = lane >> 4;
  const int m_base = (wave >> 1) * 64, n_base = (wave & 1) * 64;

  __shared__ bf16 Al[128 * 72];
  __shared__ bf16 Bl[128 * 72];

  {
    int row = t >> 3, seg = t & 7;
#pragma unroll
    for (int j = 0; j < 4; ++j) {
      int r = row + j * 32;
      *(u16x8*)&Al[r * 72 + seg * 8] = *(const u16x8*)(M23 + (size_t)r * 64 + seg * 8);
      *(bf16x8*)&Bl[r * 72 + seg * 8] =
          load8f(x, ((size_t)bs * NN + v0 + r) * 64 + seg * 8, isf);
    }
  }
  __syncthreads();

  f32x4 zero = {0.f, 0.f, 0.f, 0.f};
  f32x4 acc[4][4];
#pragma unroll
  for (int mt = 0; mt < 4; ++mt)
#pragma unroll
    for (int nt = 0; nt < 4; ++nt) acc[mt][nt] = zero;

#pragma unroll
  for (int ks = 0; ks < 2; ++ks) {
    bf16x8 af[4], bfr[4];
#pragma unroll
    for (int mt = 0; mt < 4; ++mt)
      af[mt] = *(const bf16x8*)&Al[(m_base + mt * 16 + lane_r) * 72 + ks * 32 + quad * 8];
#pragma unroll
    for (int nt = 0; nt < 4; ++nt)
      bfr[nt] = *(const bf16x8*)&Bl[(n_base + nt * 16 + lane_r) * 72 + ks * 32 + quad * 8];
#pragma unroll
    for (int mt = 0; mt < 4; ++mt)
#pragma unroll
      for (int nt = 0; nt < 4; ++nt)
        acc[mt][nt] = MFMA16(af[mt], bfr[nt], acc[mt][nt], 0, 0, 0);
  }

  bf16* dst = (m_base == 0) ? y2out : y3out;  // wave-uniform
#pragma unroll
  for (int mt = 0; mt < 4; ++mt) {
#pragma unroll
    for (int i = 0; i < 4; ++i) {
      int f = (m_base + mt * 16 + quad * 4 + i) & 63;
#pragma unroll
      for (int nt = 0; nt < 4; ++nt) {
        int v = v0 + n_base + nt * 16 + lane_r;
        dst[((size_t)bs * 64 + f) * NN + v] = (bf16)acc[mt][nt][i];
      }
    }
  }
}

// ---------------------------------------------------------------------------
// hop_add (IN-PLACE over y2): y2w[bs][e][w] += sum_v y3[bs][e][v]*aT[w][v]
// Each y2w element read once, by the thread that overwrites it. Blocks disjoint.
// ---------------------------------------------------------------------------
__global__ __launch_bounds__(256) void hop_add_kernel(
    const bf16* __restrict__ y3, const bf16* __restrict__ aT, bf16* y2w) {
  const int w0 = blockIdx.x * 128;
  const int bs0 = blockIdx.y * 2;
  const int t = threadIdx.x;
  const int wave = t >> 6, lane = t & 63;
  const int lane_r = lane & 15, quad = lane >> 4;
  const int m_base = (wave >> 1) * 64, n_base = (wave & 1) * 64;

  __shared__ bf16 Al[128 * 72];
  __shared__ bf16 Bl[128 * 72];

  f32x4 zero = {0.f, 0.f, 0.f, 0.f};
  f32x4 acc[4][4];
#pragma unroll
  for (int mt = 0; mt < 4; ++mt)
#pragma unroll
    for (int nt = 0; nt < 4; ++nt) acc[mt][nt] = zero;

  const int srow = t >> 3, sseg = t & 7;

  for (int v0 = 0; v0 < NN; v0 += 64) {
#pragma unroll
    for (int j = 0; j < 4; ++j) {
      int r = srow + j * 32;
      const bf16* src =
          y3 + ((size_t)(bs0 + (r >> 6)) * 64 + (r & 63)) * NN + v0 + sseg * 8;
      *(u16x8*)&Al[r * 72 + sseg * 8] = *(const u16x8*)src;
      const bf16* srcb = aT + (size_t)(w0 + r) * NN + v0 + sseg * 8;
      *(u16x8*)&Bl[r * 72 + sseg * 8] = *(const u16x8*)srcb;
    }
    __syncthreads();
#pragma unroll
    for (int ks = 0; ks < 2; ++ks) {
      bf16x8 af[4], bfr[4];
#pragma unroll
      for (int mt = 0; mt < 4; ++mt)
        af[mt] = *(const bf16x8*)&Al[(m_base + mt * 16 + lane_r) * 72 + ks * 32 + quad * 8];
#pragma unroll
      for (int nt = 0; nt < 4; ++nt)
        bfr[nt] = *(const bf16x8*)&Bl[(n_base + nt * 16 + lane_r) * 72 + ks * 32 + quad * 8];
#pragma unroll
      for (int mt = 0; mt < 4; ++mt)
#pragma unroll
        for (int nt = 0; nt < 4; ++nt)
          acc[mt][nt] = MFMA16(af[mt], bfr[nt], acc[mt][nt], 0, 0, 0);
    }
    __syncthreads();
  }

#pragma unroll
  for (int mt = 0; mt < 4; ++mt) {
#pragma unroll
    for (int i = 0; i < 4; ++i) {
      int m = m_base + mt * 16 + quad * 4 + i;
      int bs = bs0 + (m >> 6), e = m & 63;
      size_t row = ((size_t)bs * 64 + e) * NN;
#pragma unroll
      for (int nt = 0; nt < 4; ++nt) {
        int w = w0 + n_base + nt * 16 + lane_r;
        y2w[row + w] = (bf16)(acc[mt][nt][i] + (float)y2w[row + w]);
      }
    }
  }
}

// ---------------------------------------------------------------------------
// hop_out (IN-PLACE over y1): y1io[bs][w][e] += sum_v aT[w][v]*w23[bs][e][v] + beta[e]
// ---------------------------------------------------------------------------
__global__ __launch_bounds__(256) void hop_out_kernel(
    const bf16* __restrict__ w23, const bf16* __restrict__ aT,
    bf16* y1io, const float* __restrict__ beta) {
  const int w0 = blockIdx.x * 128;
  const int bs0 = blockIdx.y * 2;
  const int t = threadIdx.x;
  const int wave = t >> 6, lane = t & 63;
  const int lane_r = lane & 15, quad = lane >> 4;
  const int m_base = (wave >> 1) * 64, n_base = (wave & 1) * 64;

  __shared__ bf16 Al[128 * 72];
  __shared__ bf16 Bl[128 * 72];

  f32x4 zero = {0.f, 0.f, 0.f, 0.f};
  f32x4 acc[4][4];
#pragma unroll
  for (int mt = 0; mt < 4; ++mt)
#pragma unroll
    for (int nt = 0; nt < 4; ++nt) acc[mt][nt] = zero;

  const int srow = t >> 3, sseg = t & 7;

  for (int v0 = 0; v0 < NN; v0 += 64) {
#pragma unroll
    for (int j = 0; j < 4; ++j) {
      int r = srow + j * 32;
      const bf16* srca = aT + (size_t)(w0 + r) * NN + v0 + sseg * 8;
      *(u16x8*)&Al[r * 72 + sseg * 8] = *(const u16x8*)srca;
      const bf16* srcb =
          w23 + ((size_t)(bs0 + (r >> 6)) * 64 + (r & 63)) * NN + v0 + sseg * 8;
      *(u16x8*)&Bl[r * 72 + sseg * 8] = *(const u16x8*)srcb;
    }
    __syncthreads();
#pragma unroll
    for (int ks = 0; ks < 2; ++ks) {
      bf16x8 af[4], bfr[4];
#pragma unroll
      for (int mt = 0; mt < 4; ++mt)
        af[mt] = *(const bf16x8*)&Al[(m_base + mt * 16 + lane_r) * 72 + ks * 32 + quad * 8];
#pragma unroll
      for (int nt = 0; nt < 4; ++nt)
        bfr[nt] = *(const bf16x8*)&Bl[(n_base + nt * 16 + lane_r) * 72 + ks * 32 + quad * 8];
#pragma unroll
      for (int mt = 0; mt < 4; ++mt)
#pragma unroll
        for (int nt = 0; nt < 4; ++nt)
          acc[mt][nt] = MFMA16(af[mt], bfr[nt], acc[mt][nt], 0, 0, 0);
    }
    __syncthreads();
  }

#pragma unroll
  for (int mt = 0; mt < 4; ++mt) {
#pragma unroll
    for (int i = 0; i < 4; ++i) {
      int w = w0 + m_base + mt * 16 + quad * 4 + i;
#pragma unroll
      for (int nt = 0; nt < 4; ++nt) {
        int nidx = n_base + nt * 16 + lane_r;
        int bs = bs0 + (nidx >> 6), e = nidx & 63;
        size_t addr = ((size_t)bs * NN + w) * 64 + e;
        y1io[addr] = (bf16)(acc[mt][nt][i] + (float)y1io[addr] + beta[e]);
      }
    }
  }
}

// ---------------------------------------------------------------------------
// attention (IN-PLACE q->o): per (b,n) full attention over time, 8 heads DK=8.
// ---------------------------------------------------------------------------
__global__ __launch_bounds__(512) void attn_kernel(
    bf16* qo, const bf16* __restrict__ k, const bf16* __restrict__ v) {
  const int bn = blockIdx.x;
  const int b = bn / NN, n = bn % NN;
  __shared__ bf16 Qs[64 * 64];
  __shared__ bf16 Ks[64 * 64];
  __shared__ bf16 Vs[64 * 64];
  const int t = threadIdx.x;
  {
    int row = t >> 3, seg = t & 7;
    size_t g = ((size_t)(b * 64 + row) * NN + n) * 64 + seg * 8;
    *(u16x8*)&Qs[row * 64 + seg * 8] = *(const u16x8*)(qo + g);
    *(u16x8*)&Ks[row * 64 + seg * 8] = *(const u16x8*)(k + g);
    *(u16x8*)&Vs[row * 64 + seg * 8] = *(const u16x8*)(v + g);
  }
  __syncthreads();
  const int h = t >> 6, l = t & 63;
  float Qf[8];
  {
    bf16x8 qv = *(const bf16x8*)&Qs[l * 64 + h * 8];
#pragma unroll
    for (int j = 0; j < 8; ++j) Qf[j] = (float)qv[j];
  }
  float sc[64];
  float mx = -1e30f;
#pragma unroll
  for (int s = 0; s < 64; ++s) {
    bf16x8 kv = *(const bf16x8*)&Ks[s * 64 + h * 8];
    float d = 0.f;
#pragma unroll
    for (int j = 0; j < 8; ++j) d += Qf[j] * (float)kv[j];
    d *= 0.35355339059327373f;  // 1/sqrt(8)
    sc[s] = d;
    mx = fmaxf(mx, d);
  }
  float den = 0.f;
  float accv[8] = {0.f, 0.f, 0.f, 0.f, 0.f, 0.f, 0.f, 0.f};
#pragma unroll
  for (int s = 0; s < 64; ++s) {
    float wgt = __expf(sc[s] - mx);
    den += wgt;
    bf16x8 vv = *(const bf16x8*)&Vs[s * 64 + h * 8];
#pragma unroll
    for (int j = 0; j < 8; ++j) accv[j] += wgt * (float)vv[j];
  }
  float inv = 1.f / den;
  bf16x8 ov;
#pragma unroll
  for (int j = 0; j < 8; ++j) ov[j] = (bf16)(accv[j] * inv);
  *(bf16x8*)(qo + ((size_t)(b * 64 + l) * NN + n) * 64 + h * 8) = ov;
}

// ---------------------------------------------------------------------------
// workspace layout (bytes) — total 76,808,192 (~73.3 MiB)
// ---------------------------------------------------------------------------
constexpr size_t OFF_AT    = 0;            // 1,179,648
constexpr size_t OFF_MK1K  = 1179648;      // 8,192
constexpr size_t OFF_MK23K = 1187840;      // 16,384
constexpr size_t OFF_MK1V  = 1204224;      // 8,192
constexpr size_t OFF_MK23V = 1212416;      // 16,384
constexpr size_t OFF_BK    = 1228800;      // 256
constexpr size_t OFF_BV    = 1229056;      // 256
constexpr size_t OFF_WQ    = 1229312;      // 8,192
constexpr size_t OFF_BQ    = 1237504;      // 128
constexpr size_t OFF_WO    = 1237632;      // 8,192
constexpr size_t OFF_BO    = 1245824;      // 128
constexpr size_t OFF_FLAG  = 1245952;      // 64
constexpr size_t OFF_T1    = 1310720;      // 25,165,824 (K)
constexpr size_t OFF_T2    = 26476544;     // 25,165,824 (V)
constexpr size_t OFF_T3    = 51642368;     // 25,165,824 (Q / ATT)

extern "C" void kernel_launch(void* const* d_in, const int* in_sizes, int n_in,
                              void* d_out, int out_size, void* d_ws, size_t ws_size,
                              hipStream_t stream) {
  const void* queries = d_in[0];
  const void* keys    = d_in[1];
  const void* values  = d_in[2];
  const void* support = d_in[3];
  const void* Wq = d_in[4];
  const void* bq = d_in[5];
  const void* Wk = d_in[6];
  const void* bk = d_in[7];
  const void* Wv = d_in[8];
  const void* bv = d_in[9];
  const void* Wo = d_in[10];
  const void* bo = d_in[11];
  const void* Wg1 = d_in[12];
  const void* bg1 = d_in[13];
  const void* Wg2 = d_in[14];
  const void* bg2 = d_in[15];
  // query_lengths/key_lengths are full-length -> no masking needed.

  char* w = (char*)d_ws;
  bf16* AT    = (bf16*)(w + OFF_AT);
  bf16* MK1K  = (bf16*)(w + OFF_MK1K);
  bf16* MK23K = (bf16*)(w + OFF_MK23K);
  bf16* MK1V  = (bf16*)(w + OFF_MK1V);
  bf16* MK23V = (bf16*)(w + OFF_MK23V);
  float* BK   = (float*)(w + OFF_BK);
  float* BV   = (float*)(w + OFF_BV);
  bf16* WQc   = (bf16*)(w + OFF_WQ);
  bf16* BQc   = (bf16*)(w + OFF_BQ);
  bf16* WOc   = (bf16*)(w + OFF_WO);
  bf16* BOc   = (bf16*)(w + OFF_BO);
  int*  FLAG  = (int*)(w + OFF_FLAG);
  bf16* T1    = (bf16*)(w + OFF_T1);
  bf16* T2    = (bf16*)(w + OFF_T2);
  bf16* T3    = (bf16*)(w + OFF_T3);
  bf16* OUTS  = (bf16*)d_out;  // d_out's first 25MB as bf16 scratch (safe either dtype)

  // dtype detection + prep
  zero_flag_kernel<<<1, 64, 0, stream>>>(FLAG);
  detect_kernel<<<64, 256, 0, stream>>>((const unsigned short*)queries, FLAG);
  prep_aT_kernel<<<(NN * NN + 255) / 256, 256, 0, stream>>>(support, FLAG, AT);
  prep_w_kernel<<<1, 256, 0, stream>>>(Wk, bk, Wg1, bg1, FLAG, MK1K, MK23K, BK);
  prep_w_kernel<<<1, 256, 0, stream>>>(Wv, bv, Wg2, bg2, FLAG, MK1V, MK23V, BV);
  conv_qo_kernel<<<33, 256, 0, stream>>>(Wq, bq, Wo, bo, FLAG, WQc, BQc, WOc, BOc);

  // keys path: K = y1 + aT*(y2 + aT*y3) + beta
  projT_kernel<<<dim3(6, 256), 256, 0, stream>>>(keys, MK23K, T2 /*y2*/, T1 /*y3*/, FLAG);
  hop_add_kernel<<<dim3(6, 128), 256, 0, stream>>>(T1, AT, T2);            // T2 := w23K
  proj_rows_kernel<<<RROWS / 128, 256, 0, stream>>>(keys, MK1K, nullptr, T1, FLAG, 1, 0);
  hop_out_kernel<<<dim3(6, 128), 256, 0, stream>>>(T2, AT, T1, BK);        // T1 := K

  // values path (y2/w23 scratch lives in d_out's first 25MB)
  projT_kernel<<<dim3(6, 256), 256, 0, stream>>>(values, MK23V, OUTS /*y2*/, T2 /*y3*/, FLAG);
  hop_add_kernel<<<dim3(6, 128), 256, 0, stream>>>(T2, AT, OUTS);          // OUTS := w23V
  proj_rows_kernel<<<RROWS / 128, 256, 0, stream>>>(values, MK1V, nullptr, T2, FLAG, 1, 0);
  hop_out_kernel<<<dim3(6, 128), 256, 0, stream>>>(OUTS, AT, T2, BV);      // T2 := V

  // q projection -> T3, attention in-place on T3, output projection T3 -> d_out
  proj_rows_kernel<<<RROWS / 128, 256, 0, stream>>>(queries, WQc, BQc, T3, FLAG, 1, 0);
  attn_kernel<<<NB * NN, 512, 0, stream>>>(T3, T1, T2);
  proj_rows_kernel<<<RROWS / 128, 256, 0, stream>>>(T3, WOc, BOc, d_out, FLAG, 0, 1);
}

// Round 4
// 637.772 us; speedup vs baseline: 2.1608x; 2.1608x over previous
//
#include <hip/hip_runtime.h>

typedef __bf16 bf16;
typedef __attribute__((ext_vector_type(8))) __bf16 bf16x8;
typedef __attribute__((ext_vector_type(4))) float f32x4;
typedef __attribute__((ext_vector_type(8))) unsigned short u16x8;

#define MFMA16 __builtin_amdgcn_mfma_f32_16x16x32_bf16

// Problem constants
constexpr int NB = 4;      // B
constexpr int NL = 64;     // L == S
constexpr int NN = 768;    // nodes
constexpr int RROWS = NB * NL * NN;  // 196608 flat rows

// ---------------------------------------------------------------------------
// dtype-dispatch helpers: external inputs may be fp32 or bf16 (runtime flag)
// ---------------------------------------------------------------------------
__device__ __forceinline__ float loadsf(const void* base, size_t i, int isf) {
  return isf ? ((const float*)base)[i] : (float)((const bf16*)base)[i];
}

__device__ __forceinline__ bf16x8 load8f(const void* base, size_t eoff, int isf) {
  if (isf) {
    const float* p = (const float*)base + eoff;
    f32x4 a = *(const f32x4*)(p);
    f32x4 b = *(const f32x4*)(p + 4);
    bf16x8 r;
    r[0] = (bf16)a[0]; r[1] = (bf16)a[1]; r[2] = (bf16)a[2]; r[3] = (bf16)a[3];
    r[4] = (bf16)b[0]; r[5] = (bf16)b[1]; r[6] = (bf16)b[2]; r[7] = (bf16)b[3];
    return r;
  }
  return *(const bf16x8*)((const bf16*)base + eoff);
}

// ---------------------------------------------------------------------------
// flag: 1 if external tensors are fp32 (detected via bf16-NaN bit patterns
// appearing when fp32 mantissa halves are read as bf16), else 0.
// ---------------------------------------------------------------------------
__global__ void zero_flag_kernel(int* flag) { if (threadIdx.x == 0) *flag = 0; }

__global__ void detect_kernel(const unsigned short* __restrict__ q, int* flag) {
  size_t idx = (size_t)blockIdx.x * 256 + threadIdx.x;
  int found = 0;
  constexpr size_t CHUNKS = 12582912 / 8;  // scan 12.58M u16 (whole bf16 buf / half fp32 buf)
  for (size_t c = idx; c < CHUNKS; c += (size_t)64 * 256) {
    u16x8 v = *(const u16x8*)(q + c * 8);
#pragma unroll
    for (int j = 0; j < 8; ++j)
      if ((v[j] & 0x7F80) == 0x7F80) found = 1;  // exp all-ones: NaN/Inf bf16 pattern
  }
  if (__ballot(found)) {
    if ((threadIdx.x & 63) == 0) atomicOr(flag, 1);
  }
}

// ---------------------------------------------------------------------------
// prep: aT[w][v] = a[v][w]
// ---------------------------------------------------------------------------
__global__ void prep_aT_kernel(const void* __restrict__ a, const int* __restrict__ flagp,
                               bf16* __restrict__ aT) {
  const int isf = *flagp;
  int idx = blockIdx.x * 256 + threadIdx.x;
  if (idx < NN * NN) {
    int w = idx / NN, v = idx % NN;
    aT[idx] = (bf16)loadsf(a, (size_t)v * NN + w, isf);
  }
}

// ---------------------------------------------------------------------------
// prep: combined weights.  M_j[e,c] = sum_o Wp[e,o] * Wg[o, j*64+c]  (j=0,1,2)
//       beta[e] = sum_o Wp[e,o]*bg[o] + bp[e]
// Parallel: grid=48 blocks x 256 thr, one output element per thread.
// ---------------------------------------------------------------------------
__global__ void prep_w_kernel(const void* __restrict__ Wp, const void* __restrict__ bp,
                              const void* __restrict__ Wg, const void* __restrict__ bg,
                              const int* __restrict__ flagp,
                              bf16* __restrict__ M1, bf16* __restrict__ M23,
                              float* __restrict__ beta) {
  const int isf = *flagp;
  int idx = blockIdx.x * 256 + threadIdx.x;
  if (idx < 3 * 4096) {
    int j = idx >> 12, rem = idx & 4095, e = rem >> 6, c = rem & 63;
    float s = 0.f;
#pragma unroll 8
    for (int o = 0; o < 64; ++o)
      s += loadsf(Wp, e * 64 + o, isf) * loadsf(Wg, o * 192 + j * 64 + c, isf);
    if (j == 0) M1[e * 64 + c] = (bf16)s;
    else        M23[((j - 1) * 64 + e) * 64 + c] = (bf16)s;
  }
  if (blockIdx.x == 0 && threadIdx.x < 64) {
    int t = threadIdx.x;
    float s = loadsf(bp, t, isf);
#pragma unroll 8
    for (int o = 0; o < 64; ++o) s += loadsf(Wp, t * 64 + o, isf) * loadsf(bg, o, isf);
    beta[t] = s;
  }
}

// ---------------------------------------------------------------------------
// convert Wq,bq,Wo,bo -> internal bf16 slots
// ---------------------------------------------------------------------------
__global__ void conv_qo_kernel(const void* __restrict__ Wq, const void* __restrict__ bq,
                               const void* __restrict__ Wo, const void* __restrict__ bo,
                               const int* __restrict__ flagp,
                               bf16* __restrict__ WQc, bf16* __restrict__ BQc,
                               bf16* __restrict__ WOc, bf16* __restrict__ BOc) {
  const int isf = *flagp;
  int idx = blockIdx.x * 256 + threadIdx.x;
  if (idx < 4096)      WQc[idx]        = (bf16)loadsf(Wq, idx, isf);
  else if (idx < 4160) BQc[idx - 4096] = (bf16)loadsf(bq, idx - 4096, isf);
  else if (idx < 8256) WOc[idx - 4160] = (bf16)loadsf(Wo, idx - 4160, isf);
  else if (idx < 8320) BOc[idx - 8256] = (bf16)loadsf(bo, idx - 8256, isf);
}

// ---------------------------------------------------------------------------
// proj_rows: out[r][e] = sum_c in[r][c]*W[e][c] (+bias[e]) ; r in [r0, r0+128)
// in_ext: input dtype follows flag; out_ext: output dtype follows flag.
// ---------------------------------------------------------------------------
__global__ __launch_bounds__(256) void proj_rows_kernel(
    const void* in, const bf16* __restrict__ W,
    const bf16* __restrict__ bias, void* out,
    const int* __restrict__ flagp, int in_ext, int out_ext) {
  const int isf = *flagp;
  const int inf_ = in_ext & isf, outf = out_ext & isf;
  const int r0 = blockIdx.x * 128;
  const int t = threadIdx.x;
  const int wave = t >> 6, lane = t & 63;
  const int lane_r = lane & 15, quad = lane >> 4;
  const int m_base = wave * 32;

  __shared__ bf16 Al[128 * 72];
  __shared__ bf16 Bl[64 * 72];

  {
    int row = t >> 3, seg = t & 7;
#pragma unroll
    for (int j = 0; j < 4; ++j) {
      int r = row + j * 32;
      *(bf16x8*)&Al[r * 72 + seg * 8] = load8f(in, (size_t)(r0 + r) * 64 + seg * 8, inf_);
    }
#pragma unroll
    for (int j = 0; j < 2; ++j) {
      int u = t + j * 256;
      int br = u >> 3, bs_ = u & 7;
      *(u16x8*)&Bl[br * 72 + bs_ * 8] = *(const u16x8*)(W + (size_t)br * 64 + bs_ * 8);
    }
  }
  __syncthreads();

  f32x4 zero = {0.f, 0.f, 0.f, 0.f};
  f32x4 acc[2][4];
#pragma unroll
  for (int mt = 0; mt < 2; ++mt)
#pragma unroll
    for (int nt = 0; nt < 4; ++nt) acc[mt][nt] = zero;

#pragma unroll
  for (int ks = 0; ks < 2; ++ks) {
    bf16x8 af[2], bfr[4];
#pragma unroll
    for (int mt = 0; mt < 2; ++mt)
      af[mt] = *(const bf16x8*)&Al[(m_base + mt * 16 + lane_r) * 72 + ks * 32 + quad * 8];
#pragma unroll
    for (int nt = 0; nt < 4; ++nt)
      bfr[nt] = *(const bf16x8*)&Bl[(nt * 16 + lane_r) * 72 + ks * 32 + quad * 8];
#pragma unroll
    for (int mt = 0; mt < 2; ++mt)
#pragma unroll
      for (int nt = 0; nt < 4; ++nt)
        acc[mt][nt] = MFMA16(af[mt], bfr[nt], acc[mt][nt], 0, 0, 0);
  }

  float bv[4];
#pragma unroll
  for (int nt = 0; nt < 4; ++nt) bv[nt] = bias ? (float)bias[nt * 16 + lane_r] : 0.f;
#pragma unroll
  for (int mt = 0; mt < 2; ++mt) {
#pragma unroll
    for (int i = 0; i < 4; ++i) {
      int r = r0 + m_base + mt * 16 + quad * 4 + i;
#pragma unroll
      for (int nt = 0; nt < 4; ++nt) {
        float val = acc[mt][nt][i] + bv[nt];
        size_t o = (size_t)r * 64 + nt * 16 + lane_r;
        if (outf) ((float*)out)[o] = val;
        else      ((bf16*)out)[o] = (bf16)val;
      }
    }
  }
}

// ---------------------------------------------------------------------------
// projT: y{2,3}[bs][f][v] = sum_c M23[f(+64)][c] * x[bs*768+v][c]
// per block: one bs, 128-wide v tile. M=128(f), N=128(v), K=64.
// ---------------------------------------------------------------------------
__global__ __launch_bounds__(256) void projT_kernel(
    const void* __restrict__ x, const bf16* __restrict__ M23,
    bf16* __restrict__ y2out, bf16* __restrict__ y3out,
    const int* __restrict__ flagp) {
  const int isf = *flagp;
  const int v0 = blockIdx.x * 128;
  const int bs = blockIdx.y;
  const int t = threadIdx.x;
  const int wave = t >> 6, lane = t & 63;
  const int lane_r = lane & 15, quad = lane >> 4;
  const int m_base = (wave >> 1) * 64, n_base = (wave & 1) * 64;

  __shared__ bf16 Al[128 * 72];
  __shared__ bf16 Bl[128 * 72];

  {
    int row = t >> 3, seg = t & 7;
#pragma unroll
    for (int j = 0; j < 4; ++j) {
      int r = row + j * 32;
      *(u16x8*)&Al[r * 72 + seg * 8] = *(const u16x8*)(M23 + (size_t)r * 64 + seg * 8);
      *(bf16x8*)&Bl[r * 72 + seg * 8] =
          load8f(x, ((size_t)bs * NN + v0 + r) * 64 + seg * 8, isf);
    }
  }
  __syncthreads();

  f32x4 zero = {0.f, 0.f, 0.f, 0.f};
  f32x4 acc[4][4];
#pragma unroll
  for (int mt = 0; mt < 4; ++mt)
#pragma unroll
    for (int nt = 0; nt < 4; ++nt) acc[mt][nt] = zero;

#pragma unroll
  for (int ks = 0; ks < 2; ++ks) {
    bf16x8 af[4], bfr[4];
#pragma unroll
    for (int mt = 0; mt < 4; ++mt)
      af[mt] = *(const bf16x8*)&Al[(m_base + mt * 16 + lane_r) * 72 + ks * 32 + quad * 8];
#pragma unroll
    for (int nt = 0; nt < 4; ++nt)
      bfr[nt] = *(const bf16x8*)&Bl[(n_base + nt * 16 + lane_r) * 72 + ks * 32 + quad * 8];
#pragma unroll
    for (int mt = 0; mt < 4; ++mt)
#pragma unroll
      for (int nt = 0; nt < 4; ++nt)
        acc[mt][nt] = MFMA16(af[mt], bfr[nt], acc[mt][nt], 0, 0, 0);
  }

  bf16* dst = (m_base == 0) ? y2out : y3out;  // wave-uniform
#pragma unroll
  for (int mt = 0; mt < 4; ++mt) {
#pragma unroll
    for (int i = 0; i < 4; ++i) {
      int f = (m_base + mt * 16 + quad * 4 + i) & 63;
#pragma unroll
      for (int nt = 0; nt < 4; ++nt) {
        int v = v0 + n_base + nt * 16 + lane_r;
        dst[((size_t)bs * 64 + f) * NN + v] = (bf16)acc[mt][nt][i];
      }
    }
  }
}

// ---------------------------------------------------------------------------
// hop_add (IN-PLACE over y2): y2w[bs][e][w] += sum_v y3[bs][e][v]*aT[w][v]
// Each y2w element read once, by the thread that overwrites it. Blocks disjoint.
// ---------------------------------------------------------------------------
__global__ __launch_bounds__(256) void hop_add_kernel(
    const bf16* __restrict__ y3, const bf16* __restrict__ aT, bf16* y2w) {
  const int w0 = blockIdx.x * 128;
  const int bs0 = blockIdx.y * 2;
  const int t = threadIdx.x;
  const int wave = t >> 6, lane = t & 63;
  const int lane_r = lane & 15, quad = lane >> 4;
  const int m_base = (wave >> 1) * 64, n_base = (wave & 1) * 64;

  __shared__ bf16 Al[128 * 72];
  __shared__ bf16 Bl[128 * 72];

  f32x4 zero = {0.f, 0.f, 0.f, 0.f};
  f32x4 acc[4][4];
#pragma unroll
  for (int mt = 0; mt < 4; ++mt)
#pragma unroll
    for (int nt = 0; nt < 4; ++nt) acc[mt][nt] = zero;

  const int srow = t >> 3, sseg = t & 7;

  for (int v0 = 0; v0 < NN; v0 += 64) {
#pragma unroll
    for (int j = 0; j < 4; ++j) {
      int r = srow + j * 32;
      const bf16* src =
          y3 + ((size_t)(bs0 + (r >> 6)) * 64 + (r & 63)) * NN + v0 + sseg * 8;
      *(u16x8*)&Al[r * 72 + sseg * 8] = *(const u16x8*)src;
      const bf16* srcb = aT + (size_t)(w0 + r) * NN + v0 + sseg * 8;
      *(u16x8*)&Bl[r * 72 + sseg * 8] = *(const u16x8*)srcb;
    }
    __syncthreads();
#pragma unroll
    for (int ks = 0; ks < 2; ++ks) {
      bf16x8 af[4], bfr[4];
#pragma unroll
      for (int mt = 0; mt < 4; ++mt)
        af[mt] = *(const bf16x8*)&Al[(m_base + mt * 16 + lane_r) * 72 + ks * 32 + quad * 8];
#pragma unroll
      for (int nt = 0; nt < 4; ++nt)
        bfr[nt] = *(const bf16x8*)&Bl[(n_base + nt * 16 + lane_r) * 72 + ks * 32 + quad * 8];
#pragma unroll
      for (int mt = 0; mt < 4; ++mt)
#pragma unroll
        for (int nt = 0; nt < 4; ++nt)
          acc[mt][nt] = MFMA16(af[mt], bfr[nt], acc[mt][nt], 0, 0, 0);
    }
    __syncthreads();
  }

#pragma unroll
  for (int mt = 0; mt < 4; ++mt) {
#pragma unroll
    for (int i = 0; i < 4; ++i) {
      int m = m_base + mt * 16 + quad * 4 + i;
      int bs = bs0 + (m >> 6), e = m & 63;
      size_t row = ((size_t)bs * 64 + e) * NN;
#pragma unroll
      for (int nt = 0; nt < 4; ++nt) {
        int w = w0 + n_base + nt * 16 + lane_r;
        y2w[row + w] = (bf16)(acc[mt][nt][i] + (float)y2w[row + w]);
      }
    }
  }
}

// ---------------------------------------------------------------------------
// hop_out (IN-PLACE over y1): y1io[bs][w][e] += sum_v aT[w][v]*w23[bs][e][v] + beta[e]
// ---------------------------------------------------------------------------
__global__ __launch_bounds__(256) void hop_out_kernel(
    const bf16* __restrict__ w23, const bf16* __restrict__ aT,
    bf16* y1io, const float* __restrict__ beta) {
  const int w0 = blockIdx.x * 128;
  const int bs0 = blockIdx.y * 2;
  const int t = threadIdx.x;
  const int wave = t >> 6, lane = t & 63;
  const int lane_r = lane & 15, quad = lane >> 4;
  const int m_base = (wave >> 1) * 64, n_base = (wave & 1) * 64;

  __shared__ bf16 Al[128 * 72];
  __shared__ bf16 Bl[128 * 72];

  f32x4 zero = {0.f, 0.f, 0.f, 0.f};
  f32x4 acc[4][4];
#pragma unroll
  for (int mt = 0; mt < 4; ++mt)
#pragma unroll
    for (int nt = 0; nt < 4; ++nt) acc[mt][nt] = zero;

  const int srow = t >> 3, sseg = t & 7;

  for (int v0 = 0; v0 < NN; v0 += 64) {
#pragma unroll
    for (int j = 0; j < 4; ++j) {
      int r = srow + j * 32;
      const bf16* srca = aT + (size_t)(w0 + r) * NN + v0 + sseg * 8;
      *(u16x8*)&Al[r * 72 + sseg * 8] = *(const u16x8*)srca;
      const bf16* srcb =
          w23 + ((size_t)(bs0 + (r >> 6)) * 64 + (r & 63)) * NN + v0 + sseg * 8;
      *(u16x8*)&Bl[r * 72 + sseg * 8] = *(const u16x8*)srcb;
    }
    __syncthreads();
#pragma unroll
    for (int ks = 0; ks < 2; ++ks) {
      bf16x8 af[4], bfr[4];
#pragma unroll
      for (int mt = 0; mt < 4; ++mt)
        af[mt] = *(const bf16x8*)&Al[(m_base + mt * 16 + lane_r) * 72 + ks * 32 + quad * 8];
#pragma unroll
      for (int nt = 0; nt < 4; ++nt)
        bfr[nt] = *(const bf16x8*)&Bl[(n_base + nt * 16 + lane_r) * 72 + ks * 32 + quad * 8];
#pragma unroll
      for (int mt = 0; mt < 4; ++mt)
#pragma unroll
        for (int nt = 0; nt < 4; ++nt)
          acc[mt][nt] = MFMA16(af[mt], bfr[nt], acc[mt][nt], 0, 0, 0);
    }
    __syncthreads();
  }

#pragma unroll
  for (int mt = 0; mt < 4; ++mt) {
#pragma unroll
    for (int i = 0; i < 4; ++i) {
      int w = w0 + m_base + mt * 16 + quad * 4 + i;
#pragma unroll
      for (int nt = 0; nt < 4; ++nt) {
        int nidx = n_base + nt * 16 + lane_r;
        int bs = bs0 + (nidx >> 6), e = nidx & 63;
        size_t addr = ((size_t)bs * NN + w) * 64 + e;
        y1io[addr] = (bf16)(acc[mt][nt][i] + (float)y1io[addr] + beta[e]);
      }
    }
  }
}

// ---------------------------------------------------------------------------
// attention (IN-PLACE q->o): per (b,n) full attention over time, 8 heads DK=8.
// ONLINE softmax: no per-thread score array -> no VGPR spills.
// LDS stride 72 (was 64): breaks the all-lanes-same-bank pattern on Qs reads.
// ---------------------------------------------------------------------------
__global__ __launch_bounds__(512) void attn_kernel(
    bf16* qo, const bf16* __restrict__ k, const bf16* __restrict__ v) {
  const int bn = blockIdx.x;
  const int b = bn / NN, n = bn % NN;
  __shared__ bf16 Qs[64 * 72];
  __shared__ bf16 Ks[64 * 72];
  __shared__ bf16 Vs[64 * 72];
  const int t = threadIdx.x;
  {
    int row = t >> 3, seg = t & 7;
    size_t g = ((size_t)(b * 64 + row) * NN + n) * 64 + seg * 8;
    *(u16x8*)&Qs[row * 72 + seg * 8] = *(const u16x8*)(qo + g);
    *(u16x8*)&Ks[row * 72 + seg * 8] = *(const u16x8*)(k + g);
    *(u16x8*)&Vs[row * 72 + seg * 8] = *(const u16x8*)(v + g);
  }
  __syncthreads();
  const int h = t >> 6, l = t & 63;
  float Qf[8];
  {
    bf16x8 qv = *(const bf16x8*)&Qs[l * 72 + h * 8];
#pragma unroll
    for (int j = 0; j < 8; ++j) Qf[j] = (float)qv[j];
  }
  float mx = -1e30f, den = 0.f;
  float accv[8] = {0.f, 0.f, 0.f, 0.f, 0.f, 0.f, 0.f, 0.f};
#pragma unroll 4
  for (int s = 0; s < 64; ++s) {
    bf16x8 kv = *(const bf16x8*)&Ks[s * 72 + h * 8];
    float d = 0.f;
#pragma unroll
    for (int j = 0; j < 8; ++j) d += Qf[j] * (float)kv[j];
    d *= 0.35355339059327373f;  // 1/sqrt(8)
    float nm = fmaxf(mx, d);
    float alpha = __expf(mx - nm);   // ==1 when max unchanged; ==0 on first iter
    float wgt = __expf(d - nm);
    den = den * alpha + wgt;
    bf16x8 vv = *(const bf16x8*)&Vs[s * 72 + h * 8];
#pragma unroll
    for (int j = 0; j < 8; ++j) accv[j] = accv[j] * alpha + wgt * (float)vv[j];
    mx = nm;
  }
  float inv = 1.f / den;
  bf16x8 ov;
#pragma unroll
  for (int j = 0; j < 8; ++j) ov[j] = (bf16)(accv[j] * inv);
  *(bf16x8*)(qo + ((size_t)(b * 64 + l) * NN + n) * 64 + h * 8) = ov;
}

// ---------------------------------------------------------------------------
// workspace layout (bytes) — total 76,808,192 (~73.3 MiB)
// ---------------------------------------------------------------------------
constexpr size_t OFF_AT    = 0;            // 1,179,648
constexpr size_t OFF_MK1K  = 1179648;      // 8,192
constexpr size_t OFF_MK23K = 1187840;      // 16,384
constexpr size_t OFF_MK1V  = 1204224;      // 8,192
constexpr size_t OFF_MK23V = 1212416;      // 16,384
constexpr size_t OFF_BK    = 1228800;      // 256
constexpr size_t OFF_BV    = 1229056;      // 256
constexpr size_t OFF_WQ    = 1229312;      // 8,192
constexpr size_t OFF_BQ    = 1237504;      // 128
constexpr size_t OFF_WO    = 1237632;      // 8,192
constexpr size_t OFF_BO    = 1245824;      // 128
constexpr size_t OFF_FLAG  = 1245952;      // 64
constexpr size_t OFF_T1    = 1310720;      // 25,165,824 (K)
constexpr size_t OFF_T2    = 26476544;     // 25,165,824 (V)
constexpr size_t OFF_T3    = 51642368;     // 25,165,824 (Q / ATT)

extern "C" void kernel_launch(void* const* d_in, const int* in_sizes, int n_in,
                              void* d_out, int out_size, void* d_ws, size_t ws_size,
                              hipStream_t stream) {
  const void* queries = d_in[0];
  const void* keys    = d_in[1];
  const void* values  = d_in[2];
  const void* support = d_in[3];
  const void* Wq = d_in[4];
  const void* bq = d_in[5];
  const void* Wk = d_in[6];
  const void* bk = d_in[7];
  const void* Wv = d_in[8];
  const void* bv = d_in[9];
  const void* Wo = d_in[10];
  const void* bo = d_in[11];
  const void* Wg1 = d_in[12];
  const void* bg1 = d_in[13];
  const void* Wg2 = d_in[14];
  const void* bg2 = d_in[15];
  // query_lengths/key_lengths are full-length -> no masking needed.

  char* w = (char*)d_ws;
  bf16* AT    = (bf16*)(w + OFF_AT);
  bf16* MK1K  = (bf16*)(w + OFF_MK1K);
  bf16* MK23K = (bf16*)(w + OFF_MK23K);
  bf16* MK1V  = (bf16*)(w + OFF_MK1V);
  bf16* MK23V = (bf16*)(w + OFF_MK23V);
  float* BK   = (float*)(w + OFF_BK);
  float* BV   = (float*)(w + OFF_BV);
  bf16* WQc   = (bf16*)(w + OFF_WQ);
  bf16* BQc   = (bf16*)(w + OFF_BQ);
  bf16* WOc   = (bf16*)(w + OFF_WO);
  bf16* BOc   = (bf16*)(w + OFF_BO);
  int*  FLAG  = (int*)(w + OFF_FLAG);
  bf16* T1    = (bf16*)(w + OFF_T1);
  bf16* T2    = (bf16*)(w + OFF_T2);
  bf16* T3    = (bf16*)(w + OFF_T3);
  bf16* OUTS  = (bf16*)d_out;  // d_out's first 25MB as bf16 scratch (safe either dtype)

  // dtype detection + prep
  zero_flag_kernel<<<1, 64, 0, stream>>>(FLAG);
  detect_kernel<<<64, 256, 0, stream>>>((const unsigned short*)queries, FLAG);
  prep_aT_kernel<<<(NN * NN + 255) / 256, 256, 0, stream>>>(support, FLAG, AT);
  prep_w_kernel<<<48, 256, 0, stream>>>(Wk, bk, Wg1, bg1, FLAG, MK1K, MK23K, BK);
  prep_w_kernel<<<48, 256, 0, stream>>>(Wv, bv, Wg2, bg2, FLAG, MK1V, MK23V, BV);
  conv_qo_kernel<<<33, 256, 0, stream>>>(Wq, bq, Wo, bo, FLAG, WQc, BQc, WOc, BOc);

  // keys path: K = y1 + aT*(y2 + aT*y3) + beta
  projT_kernel<<<dim3(6, 256), 256, 0, stream>>>(keys, MK23K, T2 /*y2*/, T1 /*y3*/, FLAG);
  hop_add_kernel<<<dim3(6, 128), 256, 0, stream>>>(T1, AT, T2);            // T2 := w23K
  proj_rows_kernel<<<RROWS / 128, 256, 0, stream>>>(keys, MK1K, nullptr, T1, FLAG, 1, 0);
  hop_out_kernel<<<dim3(6, 128), 256, 0, stream>>>(T2, AT, T1, BK);        // T1 := K

  // values path (y2/w23 scratch lives in d_out's first 25MB)
  projT_kernel<<<dim3(6, 256), 256, 0, stream>>>(values, MK23V, OUTS /*y2*/, T2 /*y3*/, FLAG);
  hop_add_kernel<<<dim3(6, 128), 256, 0, stream>>>(T2, AT, OUTS);          // OUTS := w23V
  proj_rows_kernel<<<RROWS / 128, 256, 0, stream>>>(values, MK1V, nullptr, T2, FLAG, 1, 0);
  hop_out_kernel<<<dim3(6, 128), 256, 0, stream>>>(OUTS, AT, T2, BV);      // T2 := V

  // q projection -> T3, attention in-place on T3, output projection T3 -> d_out
  proj_rows_kernel<<<RROWS / 128, 256, 0, stream>>>(queries, WQc, BQc, T3, FLAG, 1, 0);
  attn_kernel<<<NB * NN, 512, 0, stream>>>(T3, T1, T2);
  proj_rows_kernel<<<RROWS / 128, 256, 0, stream>>>(T3, WOc, BOc, d_out, FLAG, 0, 1);
}

// Round 5
// 574.413 us; speedup vs baseline: 2.3991x; 1.1103x over previous
//
#include <hip/hip_runtime.h>

typedef __bf16 bf16;
typedef __attribute__((ext_vector_type(8))) __bf16 bf16x8;
typedef __attribute__((ext_vector_type(4))) float f32x4;
typedef __attribute__((ext_vector_type(8))) unsigned short u16x8;

#define MFMA16 __builtin_amdgcn_mfma_f32_16x16x32_bf16

// Problem constants
constexpr int NB = 4;      // B
constexpr int NL = 64;     // L == S
constexpr int NN = 768;    // nodes
constexpr int RROWS = NB * NL * NN;  // 196608 flat rows

// ---------------------------------------------------------------------------
// dtype-dispatch helpers: external inputs may be fp32 or bf16 (runtime flag)
// ---------------------------------------------------------------------------
__device__ __forceinline__ float loadsf(const void* base, size_t i, int isf) {
  return isf ? ((const float*)base)[i] : (float)((const bf16*)base)[i];
}

__device__ __forceinline__ bf16x8 load8f(const void* base, size_t eoff, int isf) {
  if (isf) {
    const float* p = (const float*)base + eoff;
    f32x4 a = *(const f32x4*)(p);
    f32x4 b = *(const f32x4*)(p + 4);
    bf16x8 r;
    r[0] = (bf16)a[0]; r[1] = (bf16)a[1]; r[2] = (bf16)a[2]; r[3] = (bf16)a[3];
    r[4] = (bf16)b[0]; r[5] = (bf16)b[1]; r[6] = (bf16)b[2]; r[7] = (bf16)b[3];
    return r;
  }
  return *(const bf16x8*)((const bf16*)base + eoff);
}

// ---------------------------------------------------------------------------
// flag: 1 if external tensors are fp32 (detected via bf16-NaN bit patterns
// appearing when fp32 mantissa halves are read as bf16), else 0.
// ---------------------------------------------------------------------------
__global__ void zero_flag_kernel(int* flag) { if (threadIdx.x == 0) *flag = 0; }

__global__ void detect_kernel(const unsigned short* __restrict__ q, int* flag) {
  size_t idx = (size_t)blockIdx.x * 256 + threadIdx.x;
  int found = 0;
  constexpr size_t CHUNKS = 12582912 / 8;
  for (size_t c = idx; c < CHUNKS; c += (size_t)64 * 256) {
    u16x8 v = *(const u16x8*)(q + c * 8);
#pragma unroll
    for (int j = 0; j < 8; ++j)
      if ((v[j] & 0x7F80) == 0x7F80) found = 1;
  }
  if (__ballot(found)) {
    if ((threadIdx.x & 63) == 0) atomicOr(flag, 1);
  }
}

// ---------------------------------------------------------------------------
// prep: aT[w][v] = a[v][w]
// ---------------------------------------------------------------------------
__global__ void prep_aT_kernel(const void* __restrict__ a, const int* __restrict__ flagp,
                               bf16* __restrict__ aT) {
  const int isf = *flagp;
  int idx = blockIdx.x * 256 + threadIdx.x;
  if (idx < NN * NN) {
    int w = idx / NN, v = idx % NN;
    aT[idx] = (bf16)loadsf(a, (size_t)v * NN + w, isf);
  }
}

// ---------------------------------------------------------------------------
// prep: combined weights.  M_j[e,c] = sum_o Wp[e,o] * Wg[o, j*64+c]  (j=0,1,2)
// ---------------------------------------------------------------------------
__global__ void prep_w_kernel(const void* __restrict__ Wp, const void* __restrict__ bp,
                              const void* __restrict__ Wg, const void* __restrict__ bg,
                              const int* __restrict__ flagp,
                              bf16* __restrict__ M1, bf16* __restrict__ M23,
                              float* __restrict__ beta) {
  const int isf = *flagp;
  int idx = blockIdx.x * 256 + threadIdx.x;
  if (idx < 3 * 4096) {
    int j = idx >> 12, rem = idx & 4095, e = rem >> 6, c = rem & 63;
    float s = 0.f;
#pragma unroll 8
    for (int o = 0; o < 64; ++o)
      s += loadsf(Wp, e * 64 + o, isf) * loadsf(Wg, o * 192 + j * 64 + c, isf);
    if (j == 0) M1[e * 64 + c] = (bf16)s;
    else        M23[((j - 1) * 64 + e) * 64 + c] = (bf16)s;
  }
  if (blockIdx.x == 0 && threadIdx.x < 64) {
    int t = threadIdx.x;
    float s = loadsf(bp, t, isf);
#pragma unroll 8
    for (int o = 0; o < 64; ++o) s += loadsf(Wp, t * 64 + o, isf) * loadsf(bg, o, isf);
    beta[t] = s;
  }
}

// ---------------------------------------------------------------------------
// convert Wq,bq,Wo,bo -> internal bf16 slots
// ---------------------------------------------------------------------------
__global__ void conv_qo_kernel(const void* __restrict__ Wq, const void* __restrict__ bq,
                               const void* __restrict__ Wo, const void* __restrict__ bo,
                               const int* __restrict__ flagp,
                               bf16* __restrict__ WQc, bf16* __restrict__ BQc,
                               bf16* __restrict__ WOc, bf16* __restrict__ BOc) {
  const int isf = *flagp;
  int idx = blockIdx.x * 256 + threadIdx.x;
  if (idx < 4096)      WQc[idx]        = (bf16)loadsf(Wq, idx, isf);
  else if (idx < 4160) BQc[idx - 4096] = (bf16)loadsf(bq, idx - 4096, isf);
  else if (idx < 8256) WOc[idx - 4160] = (bf16)loadsf(Wo, idx - 4160, isf);
  else if (idx < 8320) BOc[idx - 8256] = (bf16)loadsf(bo, idx - 8256, isf);
}

// ---------------------------------------------------------------------------
// proj_rows: out[r][e] = sum_c in[r][c]*W[e][c] (+bias[e]) ; r in [r0, r0+128)
// ---------------------------------------------------------------------------
__global__ __launch_bounds__(256) void proj_rows_kernel(
    const void* in, const bf16* __restrict__ W,
    const bf16* __restrict__ bias, void* out,
    const int* __restrict__ flagp, int in_ext, int out_ext) {
  const int isf = *flagp;
  const int inf_ = in_ext & isf, outf = out_ext & isf;
  const int r0 = blockIdx.x * 128;
  const int t = threadIdx.x;
  const int wave = t >> 6, lane = t & 63;
  const int lane_r = lane & 15, quad = lane >> 4;
  const int m_base = wave * 32;

  __shared__ bf16 Al[128 * 72];
  __shared__ bf16 Bl[64 * 72];

  {
    int row = t >> 3, seg = t & 7;
#pragma unroll
    for (int j = 0; j < 4; ++j) {
      int r = row + j * 32;
      *(bf16x8*)&Al[r * 72 + seg * 8] = load8f(in, (size_t)(r0 + r) * 64 + seg * 8, inf_);
    }
#pragma unroll
    for (int j = 0; j < 2; ++j) {
      int u = t + j * 256;
      int br = u >> 3, bs_ = u & 7;
      *(u16x8*)&Bl[br * 72 + bs_ * 8] = *(const u16x8*)(W + (size_t)br * 64 + bs_ * 8);
    }
  }
  __syncthreads();

  f32x4 zero = {0.f, 0.f, 0.f, 0.f};
  f32x4 acc[2][4];
#pragma unroll
  for (int mt = 0; mt < 2; ++mt)
#pragma unroll
    for (int nt = 0; nt < 4; ++nt) acc[mt][nt] = zero;

#pragma unroll
  for (int ks = 0; ks < 2; ++ks) {
    bf16x8 af[2], bfr[4];
#pragma unroll
    for (int mt = 0; mt < 2; ++mt)
      af[mt] = *(const bf16x8*)&Al[(m_base + mt * 16 + lane_r) * 72 + ks * 32 + quad * 8];
#pragma unroll
    for (int nt = 0; nt < 4; ++nt)
      bfr[nt] = *(const bf16x8*)&Bl[(nt * 16 + lane_r) * 72 + ks * 32 + quad * 8];
#pragma unroll
    for (int mt = 0; mt < 2; ++mt)
#pragma unroll
      for (int nt = 0; nt < 4; ++nt)
        acc[mt][nt] = MFMA16(af[mt], bfr[nt], acc[mt][nt], 0, 0, 0);
  }

  float bv[4];
#pragma unroll
  for (int nt = 0; nt < 4; ++nt) bv[nt] = bias ? (float)bias[nt * 16 + lane_r] : 0.f;
#pragma unroll
  for (int mt = 0; mt < 2; ++mt) {
#pragma unroll
    for (int i = 0; i < 4; ++i) {
      int r = r0 + m_base + mt * 16 + quad * 4 + i;
#pragma unroll
      for (int nt = 0; nt < 4; ++nt) {
        float val = acc[mt][nt][i] + bv[nt];
        size_t o = (size_t)r * 64 + nt * 16 + lane_r;
        if (outf) ((float*)out)[o] = val;
        else      ((bf16*)out)[o] = (bf16)val;
      }
    }
  }
}

// ---------------------------------------------------------------------------
// projT: y{2,3}[bs][f][v] = sum_c M23[f(+64)][c] * x[bs*768+v][c]
// ---------------------------------------------------------------------------
__global__ __launch_bounds__(256) void projT_kernel(
    const void* __restrict__ x, const bf16* __restrict__ M23,
    bf16* __restrict__ y2out, bf16* __restrict__ y3out,
    const int* __restrict__ flagp) {
  const int isf = *flagp;
  const int v0 = blockIdx.x * 128;
  const int bs = blockIdx.y;
  const int t = threadIdx.x;
  const int wave = t >> 6, lane = t & 63;
  const int lane_r = lane & 15, quad = lane >> 4;
  const int m_base = (wave >> 1) * 64, n_base = (wave & 1) * 64;

  __shared__ bf16 Al[128 * 72];
  __shared__ bf16 Bl[128 * 72];

  {
    int row = t >> 3, seg = t & 7;
#pragma unroll
    for (int j = 0; j < 4; ++j) {
      int r = row + j * 32;
      *(u16x8*)&Al[r * 72 + seg * 8] = *(const u16x8*)(M23 + (size_t)r * 64 + seg * 8);
      *(bf16x8*)&Bl[r * 72 + seg * 8] =
          load8f(x, ((size_t)bs * NN + v0 + r) * 64 + seg * 8, isf);
    }
  }
  __syncthreads();

  f32x4 zero = {0.f, 0.f, 0.f, 0.f};
  f32x4 acc[4][4];
#pragma unroll
  for (int mt = 0; mt < 4; ++mt)
#pragma unroll
    for (int nt = 0; nt < 4; ++nt) acc[mt][nt] = zero;

#pragma unroll
  for (int ks = 0; ks < 2; ++ks) {
    bf16x8 af[4], bfr[4];
#pragma unroll
    for (int mt = 0; mt < 4; ++mt)
      af[mt] = *(const bf16x8*)&Al[(m_base + mt * 16 + lane_r) * 72 + ks * 32 + quad * 8];
#pragma unroll
    for (int nt = 0; nt < 4; ++nt)
      bfr[nt] = *(const bf16x8*)&Bl[(n_base + nt * 16 + lane_r) * 72 + ks * 32 + quad * 8];
#pragma unroll
    for (int mt = 0; mt < 4; ++mt)
#pragma unroll
      for (int nt = 0; nt < 4; ++nt)
        acc[mt][nt] = MFMA16(af[mt], bfr[nt], acc[mt][nt], 0, 0, 0);
  }

  bf16* dst = (m_base == 0) ? y2out : y3out;  // wave-uniform
#pragma unroll
  for (int mt = 0; mt < 4; ++mt) {
#pragma unroll
    for (int i = 0; i < 4; ++i) {
      int f = (m_base + mt * 16 + quad * 4 + i) & 63;
#pragma unroll
      for (int nt = 0; nt < 4; ++nt) {
        int v = v0 + n_base + nt * 16 + lane_r;
        dst[((size_t)bs * 64 + f) * NN + v] = (bf16)acc[mt][nt][i];
      }
    }
  }
}

// ---------------------------------------------------------------------------
// hop_add (IN-PLACE over y2): y2w[bs][e][w] += sum_v y3[bs][e][v]*aT[w][v]
// ---------------------------------------------------------------------------
__global__ __launch_bounds__(256) void hop_add_kernel(
    const bf16* __restrict__ y3, const bf16* __restrict__ aT, bf16* y2w) {
  const int w0 = blockIdx.x * 128;
  const int bs0 = blockIdx.y * 2;
  const int t = threadIdx.x;
  const int wave = t >> 6, lane = t & 63;
  const int lane_r = lane & 15, quad = lane >> 4;
  const int m_base = (wave >> 1) * 64, n_base = (wave & 1) * 64;

  __shared__ bf16 Al[128 * 72];
  __shared__ bf16 Bl[128 * 72];

  f32x4 zero = {0.f, 0.f, 0.f, 0.f};
  f32x4 acc[4][4];
#pragma unroll
  for (int mt = 0; mt < 4; ++mt)
#pragma unroll
    for (int nt = 0; nt < 4; ++nt) acc[mt][nt] = zero;

  const int srow = t >> 3, sseg = t & 7;

  for (int v0 = 0; v0 < NN; v0 += 64) {
#pragma unroll
    for (int j = 0; j < 4; ++j) {
      int r = srow + j * 32;
      const bf16* src =
          y3 + ((size_t)(bs0 + (r >> 6)) * 64 + (r & 63)) * NN + v0 + sseg * 8;
      *(u16x8*)&Al[r * 72 + sseg * 8] = *(const u16x8*)src;
      const bf16* srcb = aT + (size_t)(w0 + r) * NN + v0 + sseg * 8;
      *(u16x8*)&Bl[r * 72 + sseg * 8] = *(const u16x8*)srcb;
    }
    __syncthreads();
#pragma unroll
    for (int ks = 0; ks < 2; ++ks) {
      bf16x8 af[4], bfr[4];
#pragma unroll
      for (int mt = 0; mt < 4; ++mt)
        af[mt] = *(const bf16x8*)&Al[(m_base + mt * 16 + lane_r) * 72 + ks * 32 + quad * 8];
#pragma unroll
      for (int nt = 0; nt < 4; ++nt)
        bfr[nt] = *(const bf16x8*)&Bl[(n_base + nt * 16 + lane_r) * 72 + ks * 32 + quad * 8];
#pragma unroll
      for (int mt = 0; mt < 4; ++mt)
#pragma unroll
        for (int nt = 0; nt < 4; ++nt)
          acc[mt][nt] = MFMA16(af[mt], bfr[nt], acc[mt][nt], 0, 0, 0);
    }
    __syncthreads();
  }

#pragma unroll
  for (int mt = 0; mt < 4; ++mt) {
#pragma unroll
    for (int i = 0; i < 4; ++i) {
      int m = m_base + mt * 16 + quad * 4 + i;
      int bs = bs0 + (m >> 6), e = m & 63;
      size_t row = ((size_t)bs * 64 + e) * NN;
#pragma unroll
      for (int nt = 0; nt < 4; ++nt) {
        int w = w0 + n_base + nt * 16 + lane_r;
        y2w[row + w] = (bf16)(acc[mt][nt][i] + (float)y2w[row + w]);
      }
    }
  }
}

// ---------------------------------------------------------------------------
// hop_out (IN-PLACE over y1): y1io[bs][w][e] += sum_v aT[w][v]*w23[bs][e][v] + beta[e]
// ---------------------------------------------------------------------------
__global__ __launch_bounds__(256) void hop_out_kernel(
    const bf16* __restrict__ w23, const bf16* __restrict__ aT,
    bf16* y1io, const float* __restrict__ beta) {
  const int w0 = blockIdx.x * 128;
  const int bs0 = blockIdx.y * 2;
  const int t = threadIdx.x;
  const int wave = t >> 6, lane = t & 63;
  const int lane_r = lane & 15, quad = lane >> 4;
  const int m_base = (wave >> 1) * 64, n_base = (wave & 1) * 64;

  __shared__ bf16 Al[128 * 72];
  __shared__ bf16 Bl[128 * 72];

  f32x4 zero = {0.f, 0.f, 0.f, 0.f};
  f32x4 acc[4][4];
#pragma unroll
  for (int mt = 0; mt < 4; ++mt)
#pragma unroll
    for (int nt = 0; nt < 4; ++nt) acc[mt][nt] = zero;

  const int srow = t >> 3, sseg = t & 7;

  for (int v0 = 0; v0 < NN; v0 += 64) {
#pragma unroll
    for (int j = 0; j < 4; ++j) {
      int r = srow + j * 32;
      const bf16* srca = aT + (size_t)(w0 + r) * NN + v0 + sseg * 8;
      *(u16x8*)&Al[r * 72 + sseg * 8] = *(const u16x8*)srca;
      const bf16* srcb =
          w23 + ((size_t)(bs0 + (r >> 6)) * 64 + (r & 63)) * NN + v0 + sseg * 8;
      *(u16x8*)&Bl[r * 72 + sseg * 8] = *(const u16x8*)srcb;
    }
    __syncthreads();
#pragma unroll
    for (int ks = 0; ks < 2; ++ks) {
      bf16x8 af[4], bfr[4];
#pragma unroll
      for (int mt = 0; mt < 4; ++mt)
        af[mt] = *(const bf16x8*)&Al[(m_base + mt * 16 + lane_r) * 72 + ks * 32 + quad * 8];
#pragma unroll
      for (int nt = 0; nt < 4; ++nt)
        bfr[nt] = *(const bf16x8*)&Bl[(n_base + nt * 16 + lane_r) * 72 + ks * 32 + quad * 8];
#pragma unroll
      for (int mt = 0; mt < 4; ++mt)
#pragma unroll
        for (int nt = 0; nt < 4; ++nt)
          acc[mt][nt] = MFMA16(af[mt], bfr[nt], acc[mt][nt], 0, 0, 0);
    }
    __syncthreads();
  }

#pragma unroll
  for (int mt = 0; mt < 4; ++mt) {
#pragma unroll
    for (int i = 0; i < 4; ++i) {
      int w = w0 + m_base + mt * 16 + quad * 4 + i;
#pragma unroll
      for (int nt = 0; nt < 4; ++nt) {
        int nidx = n_base + nt * 16 + lane_r;
        int bs = bs0 + (nidx >> 6), e = nidx & 63;
        size_t addr = ((size_t)bs * NN + w) * 64 + e;
        y1io[addr] = (bf16)(acc[mt][nt][i] + (float)y1io[addr] + beta[e]);
      }
    }
  }
}

// ---------------------------------------------------------------------------
// attention via MFMA (IN-PLACE q->o). Block = one (b,n); 4 waves x 2 heads.
// QK^T: 16x16x32 MFMA, K padded 8->32 (quad 0 carries data). Scores exp'd
// (no max shift: |scores| << 1 by construction), P -> LDS bf16 in A-layout.
// PV: 16x16x32, K=64 over s; ones-column at n=8 accumulates den for free.
// ---------------------------------------------------------------------------
__global__ __launch_bounds__(256) void attn_kernel(
    bf16* qo, const bf16* __restrict__ k, const bf16* __restrict__ v) {
  const int bn = blockIdx.x;
  const int b = bn / NN, n = bn % NN;
  __shared__ bf16 Qs[64 * 72];
  __shared__ bf16 Ks[64 * 72];
  __shared__ bf16 Vs[64 * 72];
  __shared__ bf16 Vt[64 * 72];         // Vt[e][s] = Vs[s][e]
  __shared__ bf16 Ps[4][64 * 72];      // per-wave P (A-layout [l][s])
  const int t = threadIdx.x;           // 256
  const int wave = t >> 6, lane = t & 63;
  const int lane_m = lane & 15, quad = lane >> 4;

  // stage Q (pre-scaled by 1/sqrt(8)), K, V
  {
    int row = t >> 2;
#pragma unroll
    for (int js = 0; js < 2; ++js) {
      int seg = (t & 3) * 2 + js;
      size_t g = ((size_t)(b * 64 + row) * NN + n) * 64 + seg * 8;
      bf16x8 qv = *(const bf16x8*)(qo + g);
      bf16x8 qs;
#pragma unroll
      for (int j = 0; j < 8; ++j) qs[j] = (bf16)((float)qv[j] * 0.35355339059327373f);
      *(bf16x8*)&Qs[row * 72 + seg * 8] = qs;
      *(u16x8*)&Ks[row * 72 + seg * 8] = *(const u16x8*)(k + g);
      *(u16x8*)&Vs[row * 72 + seg * 8] = *(const u16x8*)(v + g);
    }
  }
  __syncthreads();
  // build Vt
  {
    int e = t >> 2, sbase = (t & 3) * 16;
#pragma unroll
    for (int i = 0; i < 16; ++i) Vt[e * 72 + sbase + i] = Vs[(sbase + i) * 72 + e];
  }
  __syncthreads();

  const f32x4 zf = {0.f, 0.f, 0.f, 0.f};
  const bf16x8 zb = {};
  bf16x8 ones;
#pragma unroll
  for (int j = 0; j < 8; ++j) ones[j] = (bf16)1.0f;

  for (int hh = 0; hh < 2; ++hh) {
    const int h = wave + hh * 4;

    // ---- QK^T ----
    bf16x8 aq[4], bk[4];
#pragma unroll
    for (int mt = 0; mt < 4; ++mt)
      aq[mt] = (quad == 0) ? *(const bf16x8*)&Qs[(mt * 16 + lane_m) * 72 + h * 8] : zb;
#pragma unroll
    for (int nt = 0; nt < 4; ++nt)
      bk[nt] = (quad == 0) ? *(const bf16x8*)&Ks[(nt * 16 + lane_m) * 72 + h * 8] : zb;

    // ---- exp + store P (A-layout [l][s], stride 72) ----
#pragma unroll
    for (int mt = 0; mt < 4; ++mt) {
#pragma unroll
      for (int nt = 0; nt < 4; ++nt) {
        f32x4 sc = MFMA16(aq[mt], bk[nt], zf, 0, 0, 0);
#pragma unroll
        for (int i = 0; i < 4; ++i) {
          int l = mt * 16 + quad * 4 + i;
          Ps[wave][l * 72 + nt * 16 + lane_m] = (bf16)__expf(sc[i]);
        }
      }
    }
    __syncthreads();

    // ---- P @ [V | 1] : n=lane_m<8 -> V col, n==8 -> ones (= den) ----
    f32x4 oacc[4];
#pragma unroll
    for (int mt = 0; mt < 4; ++mt) oacc[mt] = zf;
#pragma unroll
    for (int ks = 0; ks < 2; ++ks) {
      bf16x8 bv;
      if (lane_m < 8)       bv = *(const bf16x8*)&Vt[(h * 8 + lane_m) * 72 + ks * 32 + quad * 8];
      else if (lane_m == 8) bv = ones;
      else                  bv = zb;
#pragma unroll
      for (int mt = 0; mt < 4; ++mt) {
        bf16x8 ap = *(const bf16x8*)&Ps[wave][(mt * 16 + lane_m) * 72 + ks * 32 + quad * 8];
        oacc[mt] = MFMA16(ap, bv, oacc[mt], 0, 0, 0);
      }
    }

    // ---- epilogue: divide by den (from n==8 lane of own quad-group), store ----
#pragma unroll
    for (int mt = 0; mt < 4; ++mt) {
#pragma unroll
      for (int i = 0; i < 4; ++i) {
        float den = __shfl(oacc[mt][i], (lane & 48) + 8);
        float invd = 1.0f / den;
        if (lane_m < 8) {
          int l = mt * 16 + quad * 4 + i;
          qo[((size_t)(b * 64 + l) * NN + n) * 64 + h * 8 + lane_m] =
              (bf16)(oacc[mt][i] * invd);
        }
      }
    }
    __syncthreads();
  }
}

// ---------------------------------------------------------------------------
// workspace layout (bytes) — total 76,808,192 (~73.3 MiB)
// ---------------------------------------------------------------------------
constexpr size_t OFF_AT    = 0;            // 1,179,648
constexpr size_t OFF_MK1K  = 1179648;      // 8,192
constexpr size_t OFF_MK23K = 1187840;      // 16,384
constexpr size_t OFF_MK1V  = 1204224;      // 8,192
constexpr size_t OFF_MK23V = 1212416;      // 16,384
constexpr size_t OFF_BK    = 1228800;      // 256
constexpr size_t OFF_BV    = 1229056;      // 256
constexpr size_t OFF_WQ    = 1229312;      // 8,192
constexpr size_t OFF_BQ    = 1237504;      // 128
constexpr size_t OFF_WO    = 1237632;      // 8,192
constexpr size_t OFF_BO    = 1245824;      // 128
constexpr size_t OFF_FLAG  = 1245952;      // 64
constexpr size_t OFF_T1    = 1310720;      // 25,165,824 (K)
constexpr size_t OFF_T2    = 26476544;     // 25,165,824 (V)
constexpr size_t OFF_T3    = 51642368;     // 25,165,824 (Q / ATT)

extern "C" void kernel_launch(void* const* d_in, const int* in_sizes, int n_in,
                              void* d_out, int out_size, void* d_ws, size_t ws_size,
                              hipStream_t stream) {
  const void* queries = d_in[0];
  const void* keys    = d_in[1];
  const void* values  = d_in[2];
  const void* support = d_in[3];
  const void* Wq = d_in[4];
  const void* bq = d_in[5];
  const void* Wk = d_in[6];
  const void* bk = d_in[7];
  const void* Wv = d_in[8];
  const void* bv = d_in[9];
  const void* Wo = d_in[10];
  const void* bo = d_in[11];
  const void* Wg1 = d_in[12];
  const void* bg1 = d_in[13];
  const void* Wg2 = d_in[14];
  const void* bg2 = d_in[15];

  char* w = (char*)d_ws;
  bf16* AT    = (bf16*)(w + OFF_AT);
  bf16* MK1K  = (bf16*)(w + OFF_MK1K);
  bf16* MK23K = (bf16*)(w + OFF_MK23K);
  bf16* MK1V  = (bf16*)(w + OFF_MK1V);
  bf16* MK23V = (bf16*)(w + OFF_MK23V);
  float* BK   = (float*)(w + OFF_BK);
  float* BV   = (float*)(w + OFF_BV);
  bf16* WQc   = (bf16*)(w + OFF_WQ);
  bf16* BQc   = (bf16*)(w + OFF_BQ);
  bf16* WOc   = (bf16*)(w + OFF_WO);
  bf16* BOc   = (bf16*)(w + OFF_BO);
  int*  FLAG  = (int*)(w + OFF_FLAG);
  bf16* T1    = (bf16*)(w + OFF_T1);
  bf16* T2    = (bf16*)(w + OFF_T2);
  bf16* T3    = (bf16*)(w + OFF_T3);
  bf16* OUTS  = (bf16*)d_out;

  // dtype detection + prep
  zero_flag_kernel<<<1, 64, 0, stream>>>(FLAG);
  detect_kernel<<<64, 256, 0, stream>>>((const unsigned short*)queries, FLAG);
  prep_aT_kernel<<<(NN * NN + 255) / 256, 256, 0, stream>>>(support, FLAG, AT);
  prep_w_kernel<<<48, 256, 0, stream>>>(Wk, bk, Wg1, bg1, FLAG, MK1K, MK23K, BK);
  prep_w_kernel<<<48, 256, 0, stream>>>(Wv, bv, Wg2, bg2, FLAG, MK1V, MK23V, BV);
  conv_qo_kernel<<<33, 256, 0, stream>>>(Wq, bq, Wo, bo, FLAG, WQc, BQc, WOc, BOc);

  // keys path: K = y1 + aT*(y2 + aT*y3) + beta
  projT_kernel<<<dim3(6, 256), 256, 0, stream>>>(keys, MK23K, T2 /*y2*/, T1 /*y3*/, FLAG);
  hop_add_kernel<<<dim3(6, 128), 256, 0, stream>>>(T1, AT, T2);            // T2 := w23K
  proj_rows_kernel<<<RROWS / 128, 256, 0, stream>>>(keys, MK1K, nullptr, T1, FLAG, 1, 0);
  hop_out_kernel<<<dim3(6, 128), 256, 0, stream>>>(T2, AT, T1, BK);        // T1 := K

  // values path (y2/w23 scratch lives in d_out's first 25MB)
  projT_kernel<<<dim3(6, 256), 256, 0, stream>>>(values, MK23V, OUTS /*y2*/, T2 /*y3*/, FLAG);
  hop_add_kernel<<<dim3(6, 128), 256, 0, stream>>>(T2, AT, OUTS);          // OUTS := w23V
  proj_rows_kernel<<<RROWS / 128, 256, 0, stream>>>(values, MK1V, nullptr, T2, FLAG, 1, 0);
  hop_out_kernel<<<dim3(6, 128), 256, 0, stream>>>(OUTS, AT, T2, BV);      // T2 := V

  // q projection -> T3, attention in-place on T3, output projection T3 -> d_out
  proj_rows_kernel<<<RROWS / 128, 256, 0, stream>>>(queries, WQc, BQc, T3, FLAG, 1, 0);
  attn_kernel<<<NB * NN, 256, 0, stream>>>(T3, T1, T2);
  proj_rows_kernel<<<RROWS / 128, 256, 0, stream>>>(T3, WOc, BOc, d_out, FLAG, 0, 1);
}